// Round 1
// 181.211 us; speedup vs baseline: 1.0244x; 1.0244x over previous
//
#include <hip/hip_runtime.h>
#include <hip/hip_bf16.h>

typedef __bf16 bf16x8 __attribute__((ext_vector_type(8)));
typedef float floatx4 __attribute__((ext_vector_type(4)));

#define GLB_AS __attribute__((address_space(1)))
#define LDS_AS __attribute__((address_space(3)))

__device__ __forceinline__ void async_cp16(const void* g, void* l) {
  // 16B-per-lane direct global->LDS copy (global_load_lds_dwordx4).
  // LDS dest must be wave-uniform base + lane*16 -- our seg layout guarantees it.
  __builtin_amdgcn_global_load_lds((GLB_AS void*)g, (LDS_AS void*)l, 16, 0, 0);
}

__device__ __forceinline__ unsigned short f2bf(float f) {
  __bf16 b = (__bf16)f;
  return __builtin_bit_cast(unsigned short, b);
}

// ---------------------------------------------------------------------------
// Kernel 1: decode w1 bits -> bf16 {-1,0,+1} matrix [256][800] (K padded 784->800
// with zeros so the GEMM K-loop is 25 clean chunks of 32).
// ---------------------------------------------------------------------------
__global__ void decode_w1_kernel(const int* __restrict__ w1p,
                                 const int* __restrict__ m1p,
                                 unsigned short* __restrict__ w1d) {
  int t = blockIdx.x * 256 + threadIdx.x;
  if (t >= 256 * 100) return;
  int r = t / 100;
  int j = t - r * 100;
  unsigned short vals[8];
#pragma unroll
  for (int k = 0; k < 8; ++k) vals[k] = 0;
  if (j < 98) {
    unsigned int v = (unsigned int)w1p[r * 98 + j];
    unsigned int m = (unsigned int)m1p[r * 98 + j];
#pragma unroll
    for (int k = 0; k < 8; ++k) {           // MSB-first per byte (matches _unpack)
      unsigned int bit = (v >> (7 - k)) & 1u;
      unsigned int mk  = (m >> (7 - k)) & 1u;
      vals[k] = (unsigned short)(mk ? (bit ? 0x3F80u : 0xBF80u) : 0u);  // +1/-1/0 bf16
    }
  }
  uint4 pack;
  pack.x = (unsigned)vals[0] | ((unsigned)vals[1] << 16);
  pack.y = (unsigned)vals[2] | ((unsigned)vals[3] << 16);
  pack.z = (unsigned)vals[4] | ((unsigned)vals[5] << 16);
  pack.w = (unsigned)vals[6] | ((unsigned)vals[7] << 16);
  *reinterpret_cast<uint4*>(w1d + t * 8) = pack;
}

// ---------------------------------------------------------------------------
// Kernel 2: fused  h = relu(a1 * x@W1^T);  out = a2 * (h@W2^T)
// 512 blocks x 256 threads (4 waves). Block = 64 rows x all 256 h-cols.
// v2: double-buffered staging, ONE barrier per chunk, prefetch chunk t+1
// (x loads issued BEFORE the W global_load_lds so the bf16 convert's
// auto-waitcnt is vmcnt(4), leaving the W copies in flight under it).
// ---------------------------------------------------------------------------
#define BM 64
#define BK 32
#define NCH 25
#define W1LD 800
#define HS_LD 264   // 256 + 8 pad: keeps layer-2 frag reads ~conflict-free

// phase-1 LDS layout (shorts), double-buffered:
//   Ws0[256][32] @ 0      Ws1[256][32] @ 8192
//   Xs0[ 64][32] @ 16384  Xs1[ 64][32] @ 18432   (end 20480)
// phase-2 layout (shorts):
//   Hs[64][264] @ 0 .. 16895,  W2s[16][256] @ 16896 .. 20991
#define OFF_WS0 0
#define OFF_WS1 8192
#define OFF_XS0 16384
#define OFF_XS1 18432
#define OFF_HS  0
#define OFF_W2  16896

__global__ __launch_bounds__(256, 2) void fused_kernel(
    const float* __restrict__ x,
    const unsigned short* __restrict__ w1d,
    const int* __restrict__ w2p,
    const int* __restrict__ m2p,
    const float* __restrict__ a1p,
    const float* __restrict__ a2p,
    float* __restrict__ out) {
  __shared__ unsigned short smem[64 * 264 + 16 * 256];  // 41984 B (union of phases)

  const int tid  = threadIdx.x;
  const int wave = tid >> 6;
  const int lane = tid & 63;
  const int l15  = lane & 15;
  const int quad = lane >> 4;
  const int row0 = blockIdx.x * BM;

  floatx4 acc[4][4];
#pragma unroll
  for (int i = 0; i < 4; ++i)
#pragma unroll
    for (int j = 0; j < 4; ++j) acc[i][j] = (floatx4){0.f, 0.f, 0.f, 0.f};

  // --- staging helpers (all indices compile-time-static per unrolled it) ---
  auto stage_w = [&](int kc, int offW) {
#pragma unroll
    for (int it = 0; it < 4; ++it) {
      int seg = it * 256 + tid;              // [0,1024); lds off = seg*16B
      int r = seg >> 2, c = seg & 3;
      async_cp16(w1d + r * W1LD + kc * BK + c * 8, &smem[offW + seg * 8]);
    }
  };
  auto load_x = [&](int kc, float4* xv) {
#pragma unroll
    for (int it = 0; it < 2; ++it) {
      int seg = it * 256 + tid;              // [0,512)
      int r = seg >> 3, c4 = seg & 7;
      int col = kc * BK + c4 * 4;
      if (col < 784) {
        xv[it] = *reinterpret_cast<const float4*>(
            x + (size_t)(row0 + r) * 784 + col);
      } else {
        xv[it] = (float4){0.f, 0.f, 0.f, 0.f};  // K pad 784..799
      }
    }
  };
  auto cvt_write = [&](int offX, const float4* xv) {
#pragma unroll
    for (int it = 0; it < 2; ++it) {
      int seg = it * 256 + tid;
      int r = seg >> 3, c4 = seg & 7;
      ushort4 b;
      b.x = f2bf(xv[it].x); b.y = f2bf(xv[it].y);
      b.z = f2bf(xv[it].z); b.w = f2bf(xv[it].w);
      *reinterpret_cast<ushort4*>(&smem[offX + r * BK + c4 * 4]) = b;
    }
  };
  auto compute = [&](int offW, int offX) {
    bf16x8 af[4], bfr[4];
#pragma unroll
    for (int mi = 0; mi < 4; ++mi)
      af[mi] = *reinterpret_cast<const bf16x8*>(
          &smem[offX + (mi * 16 + l15) * BK + quad * 8]);
#pragma unroll
    for (int nj = 0; nj < 4; ++nj)
      bfr[nj] = *reinterpret_cast<const bf16x8*>(
          &smem[offW + (wave * 64 + nj * 16 + l15) * BK + quad * 8]);
#pragma unroll
    for (int mi = 0; mi < 4; ++mi)
#pragma unroll
      for (int nj = 0; nj < 4; ++nj)
        acc[mi][nj] = __builtin_amdgcn_mfma_f32_16x16x32_bf16(
            af[mi], bfr[nj], acc[mi][nj], 0, 0, 0);
  };

  // --- prologue: stage chunk 0 into buffer 0 ---
  {
    float4 xv[2];
    load_x(0, xv);
    stage_w(0, OFF_WS0);
    cvt_write(OFF_XS0, xv);
  }
  __syncthreads();   // buffer 0 ready (drains vmcnt+lgkm)

  // --- main loop: prefetch(t+1) || compute(t); ONE barrier per chunk ---
#pragma unroll 2
  for (int kc = 0; kc < NCH - 1; ++kc) {
    const int p = kc & 1;
    float4 xn[2];
    load_x(kc + 1, xn);                        // issue x loads FIRST
    stage_w(kc + 1, p ? OFF_WS0 : OFF_WS1);    // then async W->LDS (stay in flight)
    compute(p ? OFF_WS1 : OFF_WS0,             // MFMA on current buffer
            p ? OFF_XS1 : OFF_XS0);
    cvt_write(p ? OFF_XS0 : OFF_XS1, xn);      // auto-wait vmcnt(4): x done, W in flight
    __syncthreads();                           // drain W copies + LDS writes; swap
  }
  compute(OFF_WS0, OFF_XS0);                   // chunk 24 (even -> buffer 0)
  __syncthreads();

  // ---- epilogue layer 1: h = relu(a1*acc) -> Hs bf16 ----
  const float a1 = a1p[0];
  const float a2 = a2p[0];
#pragma unroll
  for (int mi = 0; mi < 4; ++mi) {
#pragma unroll
    for (int nj = 0; nj < 4; ++nj) {
      int col   = wave * 64 + nj * 16 + l15;
      int rbase = mi * 16 + quad * 4;
#pragma unroll
      for (int r = 0; r < 4; ++r) {
        float h = fmaxf(a1 * acc[mi][nj][r], 0.f);
        smem[OFF_HS + (rbase + r) * HS_LD + col] = f2bf(h);
      }
    }
  }
  // ---- decode w2 -> W2s[16][256] (rows 10..15 zero) ----
#pragma unroll
  for (int it = 0; it < 2; ++it) {
    int idx = it * 256 + tid;
    if (idx < 320) {
      int r = idx >> 5, j = idx & 31;
      unsigned int v = (unsigned int)w2p[r * 32 + j];
      unsigned int m = (unsigned int)m2p[r * 32 + j];
#pragma unroll
      for (int k = 0; k < 8; ++k) {
        unsigned int bit = (v >> (7 - k)) & 1u;
        unsigned int mk  = (m >> (7 - k)) & 1u;
        smem[OFF_W2 + r * 256 + j * 8 + k] =
            (unsigned short)(mk ? (bit ? 0x3F80u : 0xBF80u) : 0u);
      }
    }
  }
#pragma unroll
  for (int r = 10; r < 16; ++r) smem[OFF_W2 + r * 256 + tid] = 0;
  __syncthreads();

  // ---- layer 2: out[64][10] = Hs @ W2s^T; wave handles 16 rows, K=256 ----
  floatx4 o2 = (floatx4){0.f, 0.f, 0.f, 0.f};
#pragma unroll
  for (int ks = 0; ks < 8; ++ks) {
    bf16x8 ha = *reinterpret_cast<const bf16x8*>(
        &smem[OFF_HS + (wave * 16 + l15) * HS_LD + ks * 32 + quad * 8]);
    bf16x8 wb = *reinterpret_cast<const bf16x8*>(
        &smem[OFF_W2 + l15 * 256 + ks * 32 + quad * 8]);
    o2 = __builtin_amdgcn_mfma_f32_16x16x32_bf16(ha, wb, o2, 0, 0, 0);
  }
  if (l15 < 10) {
#pragma unroll
    for (int r = 0; r < 4; ++r) {
      int gr = row0 + wave * 16 + quad * 4 + r;
      out[(size_t)gr * 10 + l15] = a2 * o2[r];
    }
  }
}

extern "C" void kernel_launch(void* const* d_in, const int* in_sizes, int n_in,
                              void* d_out, int out_size, void* d_ws, size_t ws_size,
                              hipStream_t stream) {
  const float* x   = (const float*)d_in[0];
  const int*   w1p = (const int*)d_in[1];
  const int*   m1p = (const int*)d_in[2];
  const float* a1  = (const float*)d_in[3];
  const int*   w2p = (const int*)d_in[4];
  const int*   m2p = (const int*)d_in[5];
  const float* a2  = (const float*)d_in[6];
  unsigned short* w1d = (unsigned short*)d_ws;  // 256*800 bf16 = 400 KB scratch
  float* out = (float*)d_out;

  decode_w1_kernel<<<100, 256, 0, stream>>>(w1p, m1p, w1d);
  fused_kernel<<<512, 256, 0, stream>>>(x, w1d, w2p, m2p, a1, a2, out);
}